// Round 4
// baseline (113.468 us; speedup 1.0000x reference)
//
#include <hip/hip_runtime.h>
#include <math.h>

// RelativeGeoSymLoss: B=8, N=4096 symmetric chamfer + trans L1.
// v5: MFMA chamfer, LDS-read-bound fix. Each wave owns 2 row-strips so one
// B-tile ds_read feeds 2 MFMAs (per-CU LDS traffic halved); min accumulate
// via v_min3_f32 over tile pairs (VALU min issues halved); 32-tile chunked
// staging (8 barriers/block instead of 32).
// ws layout (uint4 granularity):
//   0      : Arow [2][B][T][64] uint4  (row frags, -2p hi/lo)          2 MB
//   2 MB   : Bcol [2][B][T][64] uint4  (col frags, g hi/lo + |g|^2)    2 MB
//   4 MB   : pw   [2][B][N] float      (|p|^2 fp32)                  256 KB
// T = N/32 tiles.

#define PTPB 256
#define CW    4     // waves per chamfer block (256 threads)
#define SA    2     // row-strips per wave
#define CHUNK 32    // B-tiles staged per LDS chunk (32 KB)

typedef __attribute__((ext_vector_type(8)))  short bf16x8;
typedef __attribute__((ext_vector_type(16))) float f32x16;

__device__ __forceinline__ unsigned short f2bf(float x) {  // RNE
    unsigned u = __float_as_uint(x);
    return (unsigned short)((u + 0x7FFFu + ((u >> 16) & 1u)) >> 16);
}
__device__ __forceinline__ float bf2f(unsigned short h) {
    return __uint_as_float(((unsigned)h) << 16);
}
__device__ __forceinline__ uint4 pack8(const unsigned short v[8]) {
    uint4 r;
    r.x = (unsigned)v[0] | ((unsigned)v[1] << 16);
    r.y = (unsigned)v[2] | ((unsigned)v[3] << 16);
    r.z = (unsigned)v[4] | ((unsigned)v[5] << 16);
    r.w = (unsigned)v[6] | ((unsigned)v[7] << 16);
    return r;
}
__device__ __forceinline__ float min3f(float a, float b, float c) {
    float d;
    asm("v_min3_f32 %0, %1, %2, %3" : "=v"(d) : "v"(a), "v"(b), "v"(c));
    return d;
}

// rel_rot = Ra @ Rb^T ; rel_trans = ta - rel_rot @ tb
__device__ __forceinline__ void rel_tf(const float* __restrict__ Ra,
                                       const float* __restrict__ ta,
                                       const float* __restrict__ Rb,
                                       const float* __restrict__ tb,
                                       float* R, float* t) {
#pragma unroll
    for (int i = 0; i < 3; i++)
#pragma unroll
        for (int k = 0; k < 3; k++)
            R[i * 3 + k] = Ra[i * 3 + 0] * Rb[k * 3 + 0]
                         + Ra[i * 3 + 1] * Rb[k * 3 + 1]
                         + Ra[i * 3 + 2] * Rb[k * 3 + 2];
#pragma unroll
    for (int i = 0; i < 3; i++)
        t[i] = ta[i] - (R[i * 3 + 0] * tb[0] + R[i * 3 + 1] * tb[1]
                      + R[i * 3 + 2] * tb[2]);
}

// Transforms + point transform + fragment packing + out init.
__global__ void k_prep(const float* __restrict__ pred_rot,
                       const float* __restrict__ pred_trans,
                       const float* __restrict__ ctx_hyp_rot,
                       const float* __restrict__ ctx_hyp_trans,
                       const float* __restrict__ gt_rot,
                       const float* __restrict__ gt_trans,
                       const float* __restrict__ ctx_gt_rot,
                       const float* __restrict__ ctx_gt_trans,
                       const float* __restrict__ mp,
                       uint4* __restrict__ Arow, uint4* __restrict__ Bcol,
                       float* __restrict__ pw,
                       float* __restrict__ out, int B, int N) {
    int idx = blockIdx.x * blockDim.x + threadIdx.x;
    if (idx >= B * N) return;
    int b = idx / N, n = idx % N;
    int T = N >> 5;
    int tile = n >> 5, ln = n & 31;
    float px = mp[idx * 3 + 0], py = mp[idx * 3 + 1], pz = mp[idx * 3 + 2];
    const unsigned short one = 0x3F80;  // bf16 1.0
    float Rm[9], tv[3];
#pragma unroll
    for (int s = 0; s < 2; s++) {
        if (s == 0)
            rel_tf(pred_rot + b * 9, pred_trans + b * 3,
                   ctx_hyp_rot + b * 9, ctx_hyp_trans + b * 3, Rm, tv);
        else
            rel_tf(gt_rot + b * 9, gt_trans + b * 3,
                   ctx_gt_rot + b * 9, ctx_gt_trans + b * 3, Rm, tv);
        float x = Rm[0] * px + Rm[1] * py + Rm[2] * pz + tv[0];
        float y = Rm[3] * px + Rm[4] * py + Rm[5] * pz + tv[1];
        float z = Rm[6] * px + Rm[7] * py + Rm[8] * pz + tv[2];
        float w = x * x + y * y + z * z;

        // A-form: hi/lo split of -2p  (K: 0-2 ah, 3-5 al, 6-8 ah, 9-11 al, 12-13 one)
        float mx = -2.0f * x, my = -2.0f * y, mz = -2.0f * z;
        unsigned short ahx = f2bf(mx), ahy = f2bf(my), ahz = f2bf(mz);
        unsigned short alx = f2bf(mx - bf2f(ahx));
        unsigned short aly = f2bf(my - bf2f(ahy));
        unsigned short alz = f2bf(mz - bf2f(ahz));
        // B-form: hi/lo split of g, |g|^2 (K: 0-2 gh, 3-5 gh, 6-8 gl, 9-11 gl, 12 gwh, 13 gwl)
        unsigned short ghx = f2bf(x), ghy = f2bf(y), ghz = f2bf(z);
        unsigned short glx = f2bf(x - bf2f(ghx));
        unsigned short gly = f2bf(y - bf2f(ghy));
        unsigned short glz = f2bf(z - bf2f(ghz));
        unsigned short gwh = f2bf(w);
        unsigned short gwl = f2bf(w - bf2f(gwh));

        unsigned short a_lo[8] = {ahx, ahy, ahz, alx, aly, alz, ahx, ahy};
        unsigned short a_hi[8] = {ahz, alx, aly, alz, one, one, 0, 0};
        unsigned short b_lo[8] = {ghx, ghy, ghz, ghx, ghy, ghz, glx, gly};
        unsigned short b_hi[8] = {glz, glx, gly, glz, gwh, gwl, 0, 0};

        size_t base = (((size_t)s * B + b) * T + tile) * 64;
        Arow[base + ln]      = pack8(a_lo);
        Arow[base + 32 + ln] = pack8(a_hi);
        Bcol[base + ln]      = pack8(b_lo);
        Bcol[base + 32 + ln] = pack8(b_hi);
        pw[((size_t)s * B + b) * N + n] = w;
    }
    if (idx == 0) {
        out[0] = 0.0f;
        float lt = 0.0f;
        for (int bb = 0; bb < B; bb++) {
            float Rp[9], tp[3], Rg[9], tg[3];
            rel_tf(pred_rot + bb * 9, pred_trans + bb * 3,
                   ctx_hyp_rot + bb * 9, ctx_hyp_trans + bb * 3, Rp, tp);
            rel_tf(gt_rot + bb * 9, gt_trans + bb * 3,
                   ctx_gt_rot + bb * 9, ctx_gt_trans + bb * 3, Rg, tg);
            lt += fabsf(tp[0] - tg[0]) + fabsf(tp[1] - tg[1]) + fabsf(tp[2] - tg[2]);
        }
        out[1] = lt / (float)(3 * B);
    }
}

// Block = 4 waves x 2 strips/wave = 8 row-strips; B-tiles staged in 32-tile
// LDS chunks (reg double-buffered). One ds_read feeds 2 MFMAs; mins via
// v_min3 over tile pairs. D[n,m] = |g_m|^2 - 2 p_n.g_m ; row-min in regs.
__global__ void __launch_bounds__(CW * 64)
k_mfma(const uint4* __restrict__ Arow, const uint4* __restrict__ Bcol,
       const float* __restrict__ pw, float* __restrict__ out, int B, int N) {
    int T = N >> 5;
    int pass = blockIdx.z, b = blockIdx.y;
    int tid = threadIdx.x, wid = tid >> 6, lane = tid & 63;
    int strip0 = (blockIdx.x * CW + wid) * SA;

    const uint4* Ap  = Arow + ((size_t)pass * B + b) * T * 64;
    const uint4* Bs  = Bcol + ((size_t)(pass ^ 1) * B + b) * T * 64;
    const float* pwp = pw + ((size_t)pass * B + b) * N;

    __shared__ uint4 sB[CHUNK * 64];   // 32 KB

    uint4 au0 = Ap[(size_t)strip0 * 64 + lane];
    uint4 au1 = Ap[(size_t)(strip0 + 1) * 64 + lane];
    bf16x8 af0 = *(bf16x8*)&au0;
    bf16x8 af1 = *(bf16x8*)&au1;

    f32x16 rmin0, rmin1, zc;
#pragma unroll
    for (int r = 0; r < 16; r++) { rmin0[r] = INFINITY; rmin1[r] = INFINITY; zc[r] = 0.0f; }

    int nch = T / CHUNK;   // 4
    uint4 stg[8];
#pragma unroll
    for (int i = 0; i < 8; i++) stg[i] = Bs[i * (CW * 64) + tid];

    for (int c = 0; c < nch; c++) {
        __syncthreads();                       // prev chunk fully consumed
#pragma unroll
        for (int i = 0; i < 8; i++) sB[i * (CW * 64) + tid] = stg[i];
        __syncthreads();                       // staged chunk visible
        if (c + 1 < nch) {
#pragma unroll
            for (int i = 0; i < 8; i++)        // prefetch next (hidden under compute)
                stg[i] = Bs[(size_t)(c + 1) * CHUNK * 64 + i * (CW * 64) + tid];
        }
#pragma unroll 4
        for (int t = 0; t < CHUNK; t += 2) {
            uint4 bu0 = sB[t * 64 + lane];
            uint4 bu1 = sB[(t + 1) * 64 + lane];
            bf16x8 bf0 = *(bf16x8*)&bu0;
            bf16x8 bf1 = *(bf16x8*)&bu1;
            f32x16 d00 = __builtin_amdgcn_mfma_f32_32x32x16_bf16(af0, bf0, zc, 0, 0, 0);
            f32x16 d01 = __builtin_amdgcn_mfma_f32_32x32x16_bf16(af0, bf1, zc, 0, 0, 0);
            f32x16 d10 = __builtin_amdgcn_mfma_f32_32x32x16_bf16(af1, bf0, zc, 0, 0, 0);
            f32x16 d11 = __builtin_amdgcn_mfma_f32_32x32x16_bf16(af1, bf1, zc, 0, 0, 0);
#pragma unroll
            for (int r = 0; r < 16; r++) {
                rmin0[r] = min3f(rmin0[r], d00[r], d01[r]);
                rmin1[r] = min3f(rmin1[r], d10[r], d11[r]);
            }
        }
    }

    // reduce over the 32 col-lanes (lane bits 0..4)
#pragma unroll
    for (int off = 1; off < 32; off <<= 1) {
#pragma unroll
        for (int r = 0; r < 16; r++) {
            rmin0[r] = fminf(rmin0[r], __shfl_xor(rmin0[r], off, 64));
            rmin1[r] = fminf(rmin1[r], __shfl_xor(rmin1[r], off, 64));
        }
    }

    float lsum = 0.0f;
    if ((lane & 31) == 0) {
        int h = lane >> 5;
        int rb0 = strip0 * 32, rb1 = rb0 + 32;
#pragma unroll
        for (int r = 0; r < 16; r++) {
            int row = (r & 3) + 8 * (r >> 2) + 4 * h;  // m74/m101 C/D map (HW-verified v4)
            lsum += sqrtf(fmaxf(rmin0[r] + pwp[rb0 + row], 0.0f));
            lsum += sqrtf(fmaxf(rmin1[r] + pwp[rb1 + row], 0.0f));
        }
    }
    lsum += __shfl_down(lsum, 32, 64);

    __shared__ float red[CW];
    if (lane == 0) red[wid] = lsum;
    __syncthreads();
    if (tid == 0) {
        float tsum = 0.0f;
#pragma unroll
        for (int w = 0; w < CW; w++) tsum += red[w];
        atomicAdd(&out[0], tsum / (float)(B * N));
    }
}

extern "C" void kernel_launch(void* const* d_in, const int* in_sizes, int n_in,
                              void* d_out, int out_size, void* d_ws, size_t ws_size,
                              hipStream_t stream) {
    const float* pred_rot      = (const float*)d_in[0];
    const float* pred_trans    = (const float*)d_in[1];
    const float* ctx_hyp_rot   = (const float*)d_in[2];
    const float* ctx_hyp_trans = (const float*)d_in[3];
    const float* gt_rot        = (const float*)d_in[4];
    const float* gt_trans      = (const float*)d_in[5];
    const float* ctx_gt_rot    = (const float*)d_in[6];
    const float* ctx_gt_trans  = (const float*)d_in[7];
    const float* model_points  = (const float*)d_in[8];

    int B = in_sizes[0] / 9;
    int N = in_sizes[8] / (3 * B);
    int T = N >> 5;
    size_t fragN = (size_t)2 * B * T * 64;   // uint4 count per array

    char* ws = (char*)d_ws;
    uint4* Arow = (uint4*)ws;
    uint4* Bcol = Arow + fragN;
    float* pw   = (float*)(Bcol + fragN);
    float* out  = (float*)d_out;

    k_prep<<<(B * N + PTPB - 1) / PTPB, PTPB, 0, stream>>>(
        pred_rot, pred_trans, ctx_hyp_rot, ctx_hyp_trans,
        gt_rot, gt_trans, ctx_gt_rot, ctx_gt_trans,
        model_points, Arow, Bcol, pw, out, B, N);

    dim3 grid(N / (CW * SA * 32), B, 2);   // (16, 8, 2) = 256 blocks, 1/CU
    k_mfma<<<grid, CW * 64, 0, stream>>>(Arow, Bcol, pw, out, B, N);
}

// Round 6
// 103.252 us; speedup vs baseline: 1.0989x; 1.0989x over previous
//
#include <hip/hip_runtime.h>
#include <math.h>

// RelativeGeoSymLoss: B=8, N=4096 symmetric chamfer + trans L1.
// v6 (resubmit after infra failure; source audited, unchanged structure):
// MFMA chamfer, SA=2 without the v5 mistakes. 8 waves/block (2/SIMD
// latency hiding); wave = (strip-pair, column-half); one B-tile ds_read
// feeds 2 MFMAs; only 2 f32x16 MFMA results live at once (no spills);
// column-half row-mins combined through a small LDS array.
// ws layout (uint4 granularity):
//   0      : Arow [2][B][T][64] uint4  (row frags, -2p hi/lo)          2 MB
//   2 MB   : Bcol [2][B][T][64] uint4  (col frags, g hi/lo + |g|^2)    2 MB
//   4 MB   : pw   [2][B][N] float      (|p|^2 fp32)                  256 KB
// T = N/32 tiles.

#define PTPB 256
#define NW   8      // waves per chamfer block (512 threads)
#define CH   16     // tiles per column-half staged per chunk (32 KB total)

typedef __attribute__((ext_vector_type(8)))  short bf16x8;
typedef __attribute__((ext_vector_type(16))) float f32x16;

__device__ __forceinline__ unsigned short f2bf(float x) {  // RNE
    unsigned u = __float_as_uint(x);
    return (unsigned short)((u + 0x7FFFu + ((u >> 16) & 1u)) >> 16);
}
__device__ __forceinline__ float bf2f(unsigned short h) {
    return __uint_as_float(((unsigned)h) << 16);
}
__device__ __forceinline__ uint4 pack8(const unsigned short v[8]) {
    uint4 r;
    r.x = (unsigned)v[0] | ((unsigned)v[1] << 16);
    r.y = (unsigned)v[2] | ((unsigned)v[3] << 16);
    r.z = (unsigned)v[4] | ((unsigned)v[5] << 16);
    r.w = (unsigned)v[6] | ((unsigned)v[7] << 16);
    return r;
}

// rel_rot = Ra @ Rb^T ; rel_trans = ta - rel_rot @ tb
__device__ __forceinline__ void rel_tf(const float* __restrict__ Ra,
                                       const float* __restrict__ ta,
                                       const float* __restrict__ Rb,
                                       const float* __restrict__ tb,
                                       float* R, float* t) {
#pragma unroll
    for (int i = 0; i < 3; i++)
#pragma unroll
        for (int k = 0; k < 3; k++)
            R[i * 3 + k] = Ra[i * 3 + 0] * Rb[k * 3 + 0]
                         + Ra[i * 3 + 1] * Rb[k * 3 + 1]
                         + Ra[i * 3 + 2] * Rb[k * 3 + 2];
#pragma unroll
    for (int i = 0; i < 3; i++)
        t[i] = ta[i] - (R[i * 3 + 0] * tb[0] + R[i * 3 + 1] * tb[1]
                      + R[i * 3 + 2] * tb[2]);
}

// Transforms + point transform + fragment packing + out init.
__global__ void k_prep(const float* __restrict__ pred_rot,
                       const float* __restrict__ pred_trans,
                       const float* __restrict__ ctx_hyp_rot,
                       const float* __restrict__ ctx_hyp_trans,
                       const float* __restrict__ gt_rot,
                       const float* __restrict__ gt_trans,
                       const float* __restrict__ ctx_gt_rot,
                       const float* __restrict__ ctx_gt_trans,
                       const float* __restrict__ mp,
                       uint4* __restrict__ Arow, uint4* __restrict__ Bcol,
                       float* __restrict__ pw,
                       float* __restrict__ out, int B, int N) {
    int idx = blockIdx.x * blockDim.x + threadIdx.x;
    if (idx >= B * N) return;
    int b = idx / N, n = idx % N;
    int T = N >> 5;
    int tile = n >> 5, ln = n & 31;
    float px = mp[idx * 3 + 0], py = mp[idx * 3 + 1], pz = mp[idx * 3 + 2];
    const unsigned short one = 0x3F80;  // bf16 1.0
    float Rm[9], tv[3];
#pragma unroll
    for (int s = 0; s < 2; s++) {
        if (s == 0)
            rel_tf(pred_rot + b * 9, pred_trans + b * 3,
                   ctx_hyp_rot + b * 9, ctx_hyp_trans + b * 3, Rm, tv);
        else
            rel_tf(gt_rot + b * 9, gt_trans + b * 3,
                   ctx_gt_rot + b * 9, ctx_gt_trans + b * 3, Rm, tv);
        float x = Rm[0] * px + Rm[1] * py + Rm[2] * pz + tv[0];
        float y = Rm[3] * px + Rm[4] * py + Rm[5] * pz + tv[1];
        float z = Rm[6] * px + Rm[7] * py + Rm[8] * pz + tv[2];
        float w = x * x + y * y + z * z;

        // A: hi/lo of -2p (K: 0-2 ah, 3-5 al, 6-8 ah, 9-11 al, 12-13 one)
        float mx = -2.0f * x, my = -2.0f * y, mz = -2.0f * z;
        unsigned short ahx = f2bf(mx), ahy = f2bf(my), ahz = f2bf(mz);
        unsigned short alx = f2bf(mx - bf2f(ahx));
        unsigned short aly = f2bf(my - bf2f(ahy));
        unsigned short alz = f2bf(mz - bf2f(ahz));
        // B: hi/lo of g, |g|^2 (K: 0-2 gh, 3-5 gh, 6-8 gl, 9-11 gl, 12 gwh, 13 gwl)
        unsigned short ghx = f2bf(x), ghy = f2bf(y), ghz = f2bf(z);
        unsigned short glx = f2bf(x - bf2f(ghx));
        unsigned short gly = f2bf(y - bf2f(ghy));
        unsigned short glz = f2bf(z - bf2f(ghz));
        unsigned short gwh = f2bf(w);
        unsigned short gwl = f2bf(w - bf2f(gwh));

        unsigned short a_lo[8] = {ahx, ahy, ahz, alx, aly, alz, ahx, ahy};
        unsigned short a_hi[8] = {ahz, alx, aly, alz, one, one, 0, 0};
        unsigned short b_lo[8] = {ghx, ghy, ghz, ghx, ghy, ghz, glx, gly};
        unsigned short b_hi[8] = {glz, glx, gly, glz, gwh, gwl, 0, 0};

        size_t base = (((size_t)s * B + b) * T + tile) * 64;
        Arow[base + ln]      = pack8(a_lo);
        Arow[base + 32 + ln] = pack8(a_hi);
        Bcol[base + ln]      = pack8(b_lo);
        Bcol[base + 32 + ln] = pack8(b_hi);
        pw[((size_t)s * B + b) * N + n] = w;
    }
    if (idx == 0) {
        out[0] = 0.0f;
        float lt = 0.0f;
        for (int bb = 0; bb < B; bb++) {
            float Rp[9], tp[3], Rg[9], tg[3];
            rel_tf(pred_rot + bb * 9, pred_trans + bb * 3,
                   ctx_hyp_rot + bb * 9, ctx_hyp_trans + bb * 3, Rp, tp);
            rel_tf(gt_rot + bb * 9, gt_trans + bb * 3,
                   ctx_gt_rot + bb * 9, ctx_gt_trans + bb * 3, Rg, tg);
            lt += fabsf(tp[0] - tg[0]) + fabsf(tp[1] - tg[1]) + fabsf(tp[2] - tg[2]);
        }
        out[1] = lt / (float)(3 * B);
    }
}

// Block = 8 waves = 4 strip-pairs x 2 column-halves; each wave: 2 strips x
// T/2 tiles. One ds_read_b128 feeds 2 MFMAs; <=2 f32x16 results live.
// D[n,m] = |g_m|^2 - 2 p_n.g_m ; column-half row-mins merged via LDS.
__global__ void __launch_bounds__(NW * 64, 2)
k_mfma(const uint4* __restrict__ Arow, const uint4* __restrict__ Bcol,
       const float* __restrict__ pw, float* __restrict__ out, int B, int N) {
    int T = N >> 5;          // 128
    int T2 = T >> 1;         // 64 tiles per column half
    int pass = blockIdx.z, b = blockIdx.y;
    int tid = threadIdx.x, wid = tid >> 6, lane = tid & 63;
    int sp = wid >> 1;       // strip-pair 0..3
    int hcol = wid & 1;      // column half
    int stripG = blockIdx.x * 8 + sp * 2;   // global strip of local strip 0

    const uint4* Ap  = Arow + ((size_t)pass * B + b) * T * 64;
    const uint4* Bs  = Bcol + ((size_t)(pass ^ 1) * B + b) * T * 64;
    const float* pwp = pw + ((size_t)pass * B + b) * N;

    __shared__ uint4 sB[2 * CH * 64];        // 32 KB: [half][tile][64]
    __shared__ float sRM[NW][2][2][16];      // 4 KB: [wave][sa][h][r]
    __shared__ float red[NW / 2];

    uint4 au0 = Ap[(size_t)stripG * 64 + lane];
    uint4 au1 = Ap[(size_t)(stripG + 1) * 64 + lane];
    bf16x8 af0 = *(bf16x8*)&au0;
    bf16x8 af1 = *(bf16x8*)&au1;

    f32x16 rmin0, rmin1, zc;
#pragma unroll
    for (int r = 0; r < 16; r++) { rmin0[r] = INFINITY; rmin1[r] = INFINITY; zc[r] = 0.0f; }

    int nch = T2 / CH;   // 4
    uint4 stg[4];
#pragma unroll
    for (int k = 0; k < 4; k++) {            // prefetch chunk 0
        int j = tid + k * 512;
        int hh = j >> 10, ti = (j & 1023) >> 6, el = j & 63;
        stg[k] = Bs[((size_t)hh * T2 + ti) * 64 + el];
    }

    for (int c = 0; c < nch; c++) {
        __syncthreads();                     // prev chunk fully consumed
#pragma unroll
        for (int k = 0; k < 4; k++) sB[tid + k * 512] = stg[k];
        __syncthreads();                     // staged chunk visible
        if (c + 1 < nch) {
#pragma unroll
            for (int k = 0; k < 4; k++) {    // prefetch next (hidden under MFMAs)
                int j = tid + k * 512;
                int hh = j >> 10, ti = (j & 1023) >> 6, el = j & 63;
                stg[k] = Bs[((size_t)hh * T2 + (c + 1) * CH + ti) * 64 + el];
            }
        }
        const uint4* sBh = sB + hcol * CH * 64;
        for (int t = 0; t < CH; t += 2) {
            uint4 bu0 = sBh[t * 64 + lane];
            uint4 bu1 = sBh[(t + 1) * 64 + lane];
            bf16x8 bf0 = *(bf16x8*)&bu0;
            bf16x8 bf1 = *(bf16x8*)&bu1;
            f32x16 d0 = __builtin_amdgcn_mfma_f32_32x32x16_bf16(af0, bf0, zc, 0, 0, 0);
            f32x16 d1 = __builtin_amdgcn_mfma_f32_32x32x16_bf16(af0, bf1, zc, 0, 0, 0);
#pragma unroll
            for (int r = 0; r < 16; r++)
                rmin0[r] = fminf(fminf(rmin0[r], d0[r]), d1[r]);   // -> v_min3
            d0 = __builtin_amdgcn_mfma_f32_32x32x16_bf16(af1, bf0, zc, 0, 0, 0);
            d1 = __builtin_amdgcn_mfma_f32_32x32x16_bf16(af1, bf1, zc, 0, 0, 0);
#pragma unroll
            for (int r = 0; r < 16; r++)
                rmin1[r] = fminf(fminf(rmin1[r], d0[r]), d1[r]);
        }
    }

    // reduce over 32 col-lanes (within each lane-half)
#pragma unroll
    for (int off = 1; off < 32; off <<= 1) {
#pragma unroll
        for (int r = 0; r < 16; r++) {
            rmin0[r] = fminf(rmin0[r], __shfl_xor(rmin0[r], off, 64));
            rmin1[r] = fminf(rmin1[r], __shfl_xor(rmin1[r], off, 64));
        }
    }
    if ((lane & 31) == 0) {
        int h = lane >> 5;
#pragma unroll
        for (int r = 0; r < 16; r++) {
            sRM[wid][0][h][r] = rmin0[r];
            sRM[wid][1][h][r] = rmin1[r];
        }
    }
    __syncthreads();

    // combine column halves: block-local row lr in 0..255
    float s = 0.0f;
    if (tid < 256) {
        int lr = tid;
        int strip = lr >> 5, rr = lr & 31;
        int wa = (strip >> 1) * 2, sa = strip & 1;
        int h = (rr >> 2) & 1;
        int r = ((rr >> 3) << 2) | (rr & 3);    // inverse of m74/m101 C/D map
        float v = fminf(sRM[wa][sa][h][r], sRM[wa + 1][sa][h][r]);
        s = sqrtf(fmaxf(v + pwp[blockIdx.x * 256 + lr], 0.0f));
    }
#pragma unroll
    for (int off = 32; off > 0; off >>= 1) s += __shfl_down(s, off, 64);
    if (lane == 0 && wid < 4) red[wid] = s;
    __syncthreads();
    if (tid == 0)
        atomicAdd(&out[0], (red[0] + red[1] + red[2] + red[3]) / (float)(B * N));
}

extern "C" void kernel_launch(void* const* d_in, const int* in_sizes, int n_in,
                              void* d_out, int out_size, void* d_ws, size_t ws_size,
                              hipStream_t stream) {
    const float* pred_rot      = (const float*)d_in[0];
    const float* pred_trans    = (const float*)d_in[1];
    const float* ctx_hyp_rot   = (const float*)d_in[2];
    const float* ctx_hyp_trans = (const float*)d_in[3];
    const float* gt_rot        = (const float*)d_in[4];
    const float* gt_trans      = (const float*)d_in[5];
    const float* ctx_gt_rot    = (const float*)d_in[6];
    const float* ctx_gt_trans  = (const float*)d_in[7];
    const float* model_points  = (const float*)d_in[8];

    int B = in_sizes[0] / 9;
    int N = in_sizes[8] / (3 * B);
    int T = N >> 5;
    size_t fragN = (size_t)2 * B * T * 64;   // uint4 count per array

    char* ws = (char*)d_ws;
    uint4* Arow = (uint4*)ws;
    uint4* Bcol = Arow + fragN;
    float* pw   = (float*)(Bcol + fragN);
    float* out  = (float*)d_out;

    k_prep<<<(B * N + PTPB - 1) / PTPB, PTPB, 0, stream>>>(
        pred_rot, pred_trans, ctx_hyp_rot, ctx_hyp_trans,
        gt_rot, gt_trans, ctx_gt_rot, ctx_gt_trans,
        model_points, Arow, Bcol, pw, out, B, N);

    dim3 grid((N >> 5) / 8, B, 2);   // (16, 8, 2) = 256 blocks, 8 waves each
    k_mfma<<<grid, NW * 64, 0, stream>>>(Arow, Bcol, pw, out, B, N);
}

// Round 7
// 94.039 us; speedup vs baseline: 1.2066x; 1.0980x over previous
//
#include <hip/hip_runtime.h>
#include <math.h>

// RelativeGeoSymLoss: B=8, N=4096 symmetric chamfer + trans L1.
// v7 = v4 verbatim (session-best, 90.9 us). MFMA chamfer: dist^2 = |p|^2 +
// |g|^2 - 2 p.g ; the -2p.g term (K=3 matmul) + |g|^2 fold computed by ONE
// v_mfma_f32_32x32x16_bf16 per 32x32 tile via fp32->bf16 hi/lo split packed
// into 14 of 16 K-slots. Two row-min passes share precomputed fragments;
// row-mins live in registers, final cross-lane reduce + per-block atomicAdd.
// (v5: SA=2/1-wave-SIMD spilled, 42us. v6: column-half split, +12us.
//  Both restructures of this loop regressed; this structure is the
//  empirical optimum.)
// ws layout (uint4 granularity):
//   0      : Arow [2][B][T][64] uint4  (row-operand frags, -2p hi/lo)  2 MB
//   2 MB   : Bcol [2][B][T][64] uint4  (col-operand frags, g hi/lo+|g|^2) 2 MB
//   4 MB   : pw   [2][B][N] float      (|p|^2 fp32)                   256 KB
// T = N/32 tiles.

#define PTPB 256
#define CW   8      // waves per chamfer block (512 threads)

typedef __attribute__((ext_vector_type(8)))  short bf16x8;
typedef __attribute__((ext_vector_type(16))) float f32x16;

__device__ __forceinline__ unsigned short f2bf(float x) {  // RNE
    unsigned u = __float_as_uint(x);
    return (unsigned short)((u + 0x7FFFu + ((u >> 16) & 1u)) >> 16);
}
__device__ __forceinline__ float bf2f(unsigned short h) {
    return __uint_as_float(((unsigned)h) << 16);
}
__device__ __forceinline__ uint4 pack8(const unsigned short v[8]) {
    uint4 r;
    r.x = (unsigned)v[0] | ((unsigned)v[1] << 16);
    r.y = (unsigned)v[2] | ((unsigned)v[3] << 16);
    r.z = (unsigned)v[4] | ((unsigned)v[5] << 16);
    r.w = (unsigned)v[6] | ((unsigned)v[7] << 16);
    return r;
}

// rel_rot = Ra @ Rb^T ; rel_trans = ta - rel_rot @ tb
__device__ __forceinline__ void rel_tf(const float* __restrict__ Ra,
                                       const float* __restrict__ ta,
                                       const float* __restrict__ Rb,
                                       const float* __restrict__ tb,
                                       float* R, float* t) {
#pragma unroll
    for (int i = 0; i < 3; i++)
#pragma unroll
        for (int k = 0; k < 3; k++)
            R[i * 3 + k] = Ra[i * 3 + 0] * Rb[k * 3 + 0]
                         + Ra[i * 3 + 1] * Rb[k * 3 + 1]
                         + Ra[i * 3 + 2] * Rb[k * 3 + 2];
#pragma unroll
    for (int i = 0; i < 3; i++)
        t[i] = ta[i] - (R[i * 3 + 0] * tb[0] + R[i * 3 + 1] * tb[1]
                      + R[i * 3 + 2] * tb[2]);
}

// Transforms + point transform + fragment packing + out init.
__global__ void k_prep(const float* __restrict__ pred_rot,
                       const float* __restrict__ pred_trans,
                       const float* __restrict__ ctx_hyp_rot,
                       const float* __restrict__ ctx_hyp_trans,
                       const float* __restrict__ gt_rot,
                       const float* __restrict__ gt_trans,
                       const float* __restrict__ ctx_gt_rot,
                       const float* __restrict__ ctx_gt_trans,
                       const float* __restrict__ mp,
                       uint4* __restrict__ Arow, uint4* __restrict__ Bcol,
                       float* __restrict__ pw,
                       float* __restrict__ out, int B, int N) {
    int idx = blockIdx.x * blockDim.x + threadIdx.x;
    if (idx >= B * N) return;
    int b = idx / N, n = idx % N;
    int T = N >> 5;
    int tile = n >> 5, ln = n & 31;
    float px = mp[idx * 3 + 0], py = mp[idx * 3 + 1], pz = mp[idx * 3 + 2];
    const unsigned short one = 0x3F80;  // bf16 1.0
    float Rm[9], tv[3];
#pragma unroll
    for (int s = 0; s < 2; s++) {
        if (s == 0)
            rel_tf(pred_rot + b * 9, pred_trans + b * 3,
                   ctx_hyp_rot + b * 9, ctx_hyp_trans + b * 3, Rm, tv);
        else
            rel_tf(gt_rot + b * 9, gt_trans + b * 3,
                   ctx_gt_rot + b * 9, ctx_gt_trans + b * 3, Rm, tv);
        float x = Rm[0] * px + Rm[1] * py + Rm[2] * pz + tv[0];
        float y = Rm[3] * px + Rm[4] * py + Rm[5] * pz + tv[1];
        float z = Rm[6] * px + Rm[7] * py + Rm[8] * pz + tv[2];
        float w = x * x + y * y + z * z;

        // A-form: hi/lo split of -2p  (K slots: 0-2 ah, 3-5 al, 6-8 ah, 9-11 al, 12-13 one)
        float mx = -2.0f * x, my = -2.0f * y, mz = -2.0f * z;
        unsigned short ahx = f2bf(mx), ahy = f2bf(my), ahz = f2bf(mz);
        unsigned short alx = f2bf(mx - bf2f(ahx));
        unsigned short aly = f2bf(my - bf2f(ahy));
        unsigned short alz = f2bf(mz - bf2f(ahz));
        // B-form: hi/lo split of g and |g|^2 (K slots: 0-2 gh, 3-5 gh, 6-8 gl, 9-11 gl, 12 gwh, 13 gwl)
        unsigned short ghx = f2bf(x), ghy = f2bf(y), ghz = f2bf(z);
        unsigned short glx = f2bf(x - bf2f(ghx));
        unsigned short gly = f2bf(y - bf2f(ghy));
        unsigned short glz = f2bf(z - bf2f(ghz));
        unsigned short gwh = f2bf(w);
        unsigned short gwl = f2bf(w - bf2f(gwh));

        unsigned short a_lo[8] = {ahx, ahy, ahz, alx, aly, alz, ahx, ahy};
        unsigned short a_hi[8] = {ahz, alx, aly, alz, one, one, 0, 0};
        unsigned short b_lo[8] = {ghx, ghy, ghz, ghx, ghy, ghz, glx, gly};
        unsigned short b_hi[8] = {glz, glx, gly, glz, gwh, gwl, 0, 0};

        size_t base = (((size_t)s * B + b) * T + tile) * 64;
        Arow[base + ln]      = pack8(a_lo);
        Arow[base + 32 + ln] = pack8(a_hi);
        Bcol[base + ln]      = pack8(b_lo);
        Bcol[base + 32 + ln] = pack8(b_hi);
        pw[((size_t)s * B + b) * N + n] = w;
    }
    if (idx == 0) {
        out[0] = 0.0f;
        float lt = 0.0f;
        for (int bb = 0; bb < B; bb++) {
            float Rp[9], tp[3], Rg[9], tg[3];
            rel_tf(pred_rot + bb * 9, pred_trans + bb * 3,
                   ctx_hyp_rot + bb * 9, ctx_hyp_trans + bb * 3, Rp, tp);
            rel_tf(gt_rot + bb * 9, gt_trans + bb * 3,
                   ctx_gt_rot + bb * 9, ctx_gt_trans + bb * 3, Rg, tg);
            lt += fabsf(tp[0] - tg[0]) + fabsf(tp[1] - tg[1]) + fabsf(tp[2] - tg[2]);
        }
        out[1] = lt / (float)(3 * B);
    }
}

// One wave = one 32-row strip x all N cols. Block = 8 waves, staging the
// shared col-fragment stream through LDS (1 tile per wave per chunk).
// MFMA output D[n,m] = |g_m|^2 - 2 p_n . g_m ; row-min accumulates in regs.
__global__ void __launch_bounds__(CW * 64)
k_mfma(const uint4* __restrict__ Arow, const uint4* __restrict__ Bcol,
       const float* __restrict__ pw, float* __restrict__ out, int B, int N) {
    int T = N >> 5;
    int pass = blockIdx.z, b = blockIdx.y;
    int tid = threadIdx.x, wid = tid >> 6, lane = tid & 63;
    int strip = blockIdx.x * CW + wid;

    const uint4* Ap  = Arow + ((size_t)pass * B + b) * T * 64;
    const uint4* Bs  = Bcol + ((size_t)(1 - pass) * B + b) * T * 64;
    const float* pwp = pw + ((size_t)pass * B + b) * N;

    __shared__ uint4 sB[CW][64];   // 8 KB

    uint4 au = Ap[(size_t)strip * 64 + lane];
    bf16x8 af = *(bf16x8*)&au;

    f32x16 rmin;
#pragma unroll
    for (int r = 0; r < 16; r++) rmin[r] = INFINITY;
    f32x16 zc;
#pragma unroll
    for (int r = 0; r < 16; r++) zc[r] = 0.0f;

    uint4 stg = Bs[(size_t)wid * 64 + lane];
    int nchunk = T / CW;   // 16
    for (int c = 0; c < nchunk; c++) {
        __syncthreads();               // prev chunk fully consumed
        sB[wid][lane] = stg;
        if (c + 1 < nchunk)
            stg = Bs[(((size_t)(c + 1)) * CW + wid) * 64 + lane];  // prefetch
        __syncthreads();               // staged chunk visible
#pragma unroll
        for (int t = 0; t < CW; t++) {
            uint4 bu = sB[t][lane];
            bf16x8 bf = *(bf16x8*)&bu;
            f32x16 d = __builtin_amdgcn_mfma_f32_32x32x16_bf16(af, bf, zc, 0, 0, 0);
#pragma unroll
            for (int r = 0; r < 16; r++) rmin[r] = fminf(rmin[r], d[r]);
        }
    }

    // reduce over the 32 col-lanes (bits 0..4 of lane)
#pragma unroll
    for (int off = 1; off < 32; off <<= 1) {
#pragma unroll
        for (int r = 0; r < 16; r++)
            rmin[r] = fminf(rmin[r], __shfl_xor(rmin[r], off, 64));
    }

    float lsum = 0.0f;
    if ((lane & 31) == 0) {
        int h = lane >> 5;
        int rowbase = strip * 32;
#pragma unroll
        for (int r = 0; r < 16; r++) {
            int row = (r & 3) + 8 * (r >> 2) + 4 * h;  // m74/m101-verified C/D map
            float v = rmin[r] + pwp[rowbase + row];
            lsum += sqrtf(fmaxf(v, 0.0f));
        }
    }
    lsum += __shfl_down(lsum, 32, 64);

    __shared__ float red[CW];
    if (lane == 0) red[wid] = lsum;
    __syncthreads();
    if (tid == 0) {
        float tsum = 0.0f;
#pragma unroll
        for (int w = 0; w < CW; w++) tsum += red[w];
        atomicAdd(&out[0], tsum / (float)(B * N));
    }
}

extern "C" void kernel_launch(void* const* d_in, const int* in_sizes, int n_in,
                              void* d_out, int out_size, void* d_ws, size_t ws_size,
                              hipStream_t stream) {
    const float* pred_rot      = (const float*)d_in[0];
    const float* pred_trans    = (const float*)d_in[1];
    const float* ctx_hyp_rot   = (const float*)d_in[2];
    const float* ctx_hyp_trans = (const float*)d_in[3];
    const float* gt_rot        = (const float*)d_in[4];
    const float* gt_trans      = (const float*)d_in[5];
    const float* ctx_gt_rot    = (const float*)d_in[6];
    const float* ctx_gt_trans  = (const float*)d_in[7];
    const float* model_points  = (const float*)d_in[8];

    int B = in_sizes[0] / 9;
    int N = in_sizes[8] / (3 * B);
    int T = N >> 5;
    size_t fragN = (size_t)2 * B * T * 64;   // uint4 count per array

    char* ws = (char*)d_ws;
    uint4* Arow = (uint4*)ws;
    uint4* Bcol = Arow + fragN;
    float* pw   = (float*)(Bcol + fragN);
    float* out  = (float*)d_out;

    k_prep<<<(B * N + PTPB - 1) / PTPB, PTPB, 0, stream>>>(
        pred_rot, pred_trans, ctx_hyp_rot, ctx_hyp_trans,
        gt_rot, gt_trans, ctx_gt_rot, ctx_gt_trans,
        model_points, Arow, Bcol, pw, out, B, N);

    dim3 grid(N / (CW * 32), B, 2);   // (16, 8, 2) = 256 blocks
    k_mfma<<<grid, CW * 64, 0, stream>>>(Arow, Bcol, pw, out, B, N);
}